// Round 9
// baseline (554.757 us; speedup 1.0000x reference)
//
#include <hip/hip_runtime.h>

#define VOCAB  82
#define EMBED  256
#define HIDDEN 128
#define BATCH  256
#define SEQ    512
#define KX     (HIDDEN + EMBED)   // 384 columns in each gate weight
#define HPAD   20                 // padded 16-float k-slice stride: slice q at
                                  // float 20q -> banks {0,20,8,28,16,4,24,12}+0..3
                                  // all 8 slices on disjoint banks, 16B-aligned

// Gate order: g=0 -> f (W_f), g=1 -> o (W_o), g=2 -> c_tilde (W_c)
__device__ __align__(16) float Gv_buf[VOCAB * 3 * HIDDEN];

__device__ __forceinline__ float vrcp(float x)  { float r; asm("v_rcp_f32 %0, %1" : "=v"(r) : "v"(x)); return r; }
__device__ __forceinline__ float vexp2(float x) { float r; asm("v_exp_f32 %0, %1" : "=v"(r) : "v"(x)); return r; }
#define LOG2E 1.4426950408889634f

// sigmoid(x) = rcp(1 + 2^(-x*log2e)) : 4 VALU ops
__device__ __forceinline__ float fast_sigmoid(float x) {
    return vrcp(1.f + vexp2(-LOG2E * x));
}
// tanh(x) = 1 - 2*rcp(1 + 2^(2*log2e*x)) : 5 ops; x->+inf: rcp(inf)=0 -> 1,
// x->-inf: rcp(1)=1 -> -1 (graceful saturation, no clamp needed)
__device__ __forceinline__ float fast_tanh(float x) {
    return fmaf(-2.f, vrcp(1.f + vexp2((2.f * LOG2E) * x)), 1.f);
}

// 8-lane butterfly sum: xor1,xor2 via DPP quad_perm; xor4 via ds_swizzle.
// All 8 lanes end with the bitwise-identical sum (fp add commutes).
__device__ __forceinline__ float oct_sum(float x) {
    int y1 = __builtin_amdgcn_mov_dpp(__float_as_int(x), 0xB1, 0xF, 0xF, true); // [1,0,3,2]
    x += __int_as_float(y1);
    int y2 = __builtin_amdgcn_mov_dpp(__float_as_int(x), 0x4E, 0xF, 0xF, true); // [2,3,0,1]
    x += __int_as_float(y2);
    int y3 = __builtin_amdgcn_ds_swizzle(__float_as_int(x), 0x101F);            // lane^4
    x += __int_as_float(y3);
    return x;
}

// Pin a value into a register: an asm def is NOT rematerializable.
#define PIN(x)  asm volatile("" : "+v"(x))
#define PIN4(v) do { PIN(v.x); PIN(v.y); PIN(v.z); PIN(v.w); } while (0)

// Raw barrier: LDS-visibility sync WITHOUT the vmcnt(0) drain, so gate
// stores stay in flight across steps (HK pattern).
__device__ __forceinline__ void block_sync_lds() {
    asm volatile("s_waitcnt lgkmcnt(0)" ::: "memory");
    __builtin_amdgcn_s_barrier();
    __builtin_amdgcn_sched_barrier(0);
}

__device__ __forceinline__ float dot16(float4 a0, float4 a1, float4 a2, float4 a3,
                                       float4 h0, float4 h1, float4 h2, float4 h3) {
    float s = a0.x * h0.x;
    s = fmaf(a0.y, h0.y, s); s = fmaf(a0.z, h0.z, s); s = fmaf(a0.w, h0.w, s);
    s = fmaf(a1.x, h1.x, s); s = fmaf(a1.y, h1.y, s); s = fmaf(a1.z, h1.z, s);
    s = fmaf(a1.w, h1.w, s);
    s = fmaf(a2.x, h2.x, s); s = fmaf(a2.y, h2.y, s); s = fmaf(a2.z, h2.z, s);
    s = fmaf(a2.w, h2.w, s);
    s = fmaf(a3.x, h3.x, s); s = fmaf(a3.y, h3.y, s); s = fmaf(a3.z, h3.z, s);
    s = fmaf(a3.w, h3.w, s);
    return s;
}

// Prologue: one block per (v,g); 128 threads = one output row each.
__global__ __launch_bounds__(128, 2)
void gv_prologue(const float* __restrict__ emb,
                 const float* __restrict__ Wf,
                 const float* __restrict__ Wc,
                 const float* __restrict__ Wo) {
    const int g = blockIdx.x % 3;
    const int v = blockIdx.x / 3;
    const int r = threadIdx.x;

    __shared__ __align__(16) float e_lds[EMBED];
    e_lds[r]       = emb[(size_t)v * EMBED + r];
    e_lds[r + 128] = emb[(size_t)v * EMBED + r + 128];
    __syncthreads();

    const float* Wg = (g == 0) ? Wf : (g == 1) ? Wo : Wc;
    const float4* wr = (const float4*)(Wg + (size_t)r * KX + HIDDEN);
    const float4* ev = (const float4*)e_lds;
    float a0 = 0.f, a1 = 0.f, a2 = 0.f, a3 = 0.f;
#pragma unroll
    for (int i = 0; i < EMBED / 4; ++i) {
        float4 w4 = wr[i];
        float4 e4 = ev[i];
        a0 += w4.x * e4.x;
        a1 += w4.y * e4.y;
        a2 += w4.z * e4.z;
        a3 += w4.w * e4.w;
    }
    Gv_buf[(size_t)v * 384 + g * 128 + r] = (a0 + a1) + (a2 + a3);
}

// Main recurrence: 256 blocks (1/CU) x 1024 threads (16 waves, 4/SIMD).
// Thread = (r = tid>>3, q = tid&7): all 3 gates of row r, k-slice [16q,16q+16).
// 48 weight floats/thread in 12 named float4s -> fits the 128-VGPR budget
// (waves_per_eu 4) without triggering the RA's remat/spill heuristic.
__global__ void __attribute__((amdgpu_flat_work_group_size(1024, 1024),
                               amdgpu_waves_per_eu(4, 4)))
lstm_main(const int* __restrict__ tokens,
          const float* __restrict__ Wf,
          const float* __restrict__ Wc,
          const float* __restrict__ Wo,
          const float* __restrict__ clfW,
          const float* __restrict__ clfb,
          float* __restrict__ out) {
    const int b   = blockIdx.x;
    const int tid = threadIdx.x;        // 0..1023
    const int q   = tid & 7;            // k-slice
    const int r   = tid >> 3;           // 0..127 output row

    __shared__ __align__(16) float hbuf[2][8 * HPAD];
    __shared__ int tok[SEQ];

    const float4* PF = (const float4*)(Wf + (size_t)r * KX + q * 16);
    const float4* PO = (const float4*)(Wo + (size_t)r * KX + q * 16);
    const float4* PC = (const float4*)(Wc + (size_t)r * KX + q * 16);
    float4 F0 = PF[0], F1 = PF[1], F2 = PF[2], F3 = PF[3];
    float4 O0 = PO[0], O1 = PO[1], O2 = PO[2], O3 = PO[3];
    float4 C0 = PC[0], C1 = PC[1], C2 = PC[2], C3 = PC[3];
    PIN4(F0); PIN4(F1); PIN4(F2); PIN4(F3);
    PIN4(O0); PIN4(O1); PIN4(O2); PIN4(O3);
    PIN4(C0); PIN4(C1); PIN4(C2); PIN4(C3);

    if (tid < SEQ)    tok[tid] = tokens[(size_t)b * SEQ + tid];
    if (tid < HIDDEN) hbuf[0][(tid >> 4) * HPAD + (tid & 15)] = 0.f;
    float c = 0.f;                      // replicated across the 8-lane team
    __syncthreads();

    const size_t GSZ = (size_t)SEQ * BATCH * HIDDEN;
    float* gout = out + (size_t)BATCH * VOCAB
                      + (size_t)(q < 3 ? q : 0) * GSZ
                      + (size_t)b * HIDDEN + r;    // dereferenced only if q<3

    for (int t = 0; t < SEQ; ++t) {
        const int p  = t & 1;
        const int tk = tok[t];
        float gx = 0.f;
        if (q < 3) gx = Gv_buf[tk * 384 + q * 128 + r];   // L2-resident

        const float4* hv = (const float4*)&hbuf[p][q * HPAD];
        float4 h0 = hv[0], h1 = hv[1], h2 = hv[2], h3 = hv[3];

        float pf = dot16(F0, F1, F2, F3, h0, h1, h2, h3);
        float po = dot16(O0, O1, O2, O3, h0, h1, h2, h3);
        float pc = dot16(C0, C1, C2, C3, h0, h1, h2, h3);
        pf += (q == 0) ? gx : 0.f;
        po += (q == 1) ? gx : 0.f;
        pc += (q == 2) ? gx : 0.f;

        pf = oct_sum(pf);
        po = oct_sum(po);
        pc = oct_sum(pc);

        const float f  = fast_sigmoid(pf);
        const float o  = fast_sigmoid(po);
        const float ct = fast_tanh(pc);
        c = fmaf(f, c - ct, ct);               // f*c + (1-f)*ct
        const float h = o * fast_tanh(c);

        if (q == 0) hbuf[1 - p][(r >> 4) * HPAD + (r & 15)] = h;
        block_sync_lds();                      // lgkmcnt(0)+s_barrier, no vmcnt drain
        const float sval = (q == 0) ? f : (q == 1) ? o : ct;
        if (q < 3) gout[(size_t)t * (BATCH * HIDDEN)] = sval;
    }

    // Epilogue: logits[b][v] = h_T . clfW[v] + clfb[v]; h_T is in hbuf[0]
    if (tid < 8 * VOCAB) {
        const int v = tid >> 3;
        const float4* cw = (const float4*)(clfW + (size_t)v * HIDDEN + q * 16);
        const float4* hp = (const float4*)&hbuf[0][q * HPAD];
        float a = dot16(cw[0], cw[1], cw[2], cw[3], hp[0], hp[1], hp[2], hp[3]);
        a = oct_sum(a);
        if (q == 0) out[(size_t)b * VOCAB + v] = a + clfb[v];
    }
}

extern "C" void kernel_launch(void* const* d_in, const int* in_sizes, int n_in,
                              void* d_out, int out_size, void* d_ws, size_t ws_size,
                              hipStream_t stream) {
    const int*   tokens = (const int*)  d_in[0];
    const float* emb    = (const float*)d_in[1];
    const float* Wf     = (const float*)d_in[2];
    const float* Wc     = (const float*)d_in[3];
    const float* Wo     = (const float*)d_in[4];
    const float* clfW   = (const float*)d_in[5];
    const float* clfb   = (const float*)d_in[6];
    float*       out    = (float*)d_out;

    gv_prologue<<<3 * VOCAB, 128, 0, stream>>>(emb, Wf, Wc, Wo);
    lstm_main<<<BATCH, 1024, 0, stream>>>(tokens, Wf, Wc, Wo, clfW, clfb, out);
}

// Round 12
// 544.198 us; speedup vs baseline: 1.0194x; 1.0194x over previous
//
#include <hip/hip_runtime.h>

#define VOCAB  82
#define EMBED  256
#define HIDDEN 128
#define BATCH  256
#define SEQ    512
#define KX     (HIDDEN + EMBED)   // 384 columns in each gate weight
#define SEG    36                 // padded LDS segment stride (32 data + 4 pad floats)

// Gate order: g=0 -> f (W_f), g=1 -> o (W_o), g=2 -> c_tilde (W_c)
__device__ __align__(16) float Gv_buf[VOCAB * 3 * HIDDEN];

__device__ __forceinline__ float vrcp(float x)  { float r; asm("v_rcp_f32 %0, %1" : "=v"(r) : "v"(x)); return r; }
__device__ __forceinline__ float vexp2(float x) { float r; asm("v_exp_f32 %0, %1" : "=v"(r) : "v"(x)); return r; }
#define LOG2E 1.4426950408889634f

// sigmoid(x) = rcp(1 + 2^(-x*log2e)) : 4 VALU ops
__device__ __forceinline__ float fast_sigmoid(float x) {
    return vrcp(1.f + vexp2(-LOG2E * x));
}
// tanh(x) = 1 - 2*rcp(1 + 2^(2*log2e*x)) : graceful saturation at +-inf
__device__ __forceinline__ float fast_tanh(float x) {
    return fmaf(-2.f, vrcp(1.f + vexp2((2.f * LOG2E) * x)), 1.f);
}

// Quad-wide sum via DPP quad_perm (pure VALU, no LDS pipe).
__device__ __forceinline__ float quad_sum(float x) {
    int y1 = __builtin_amdgcn_mov_dpp(__float_as_int(x), 0xB1, 0xF, 0xF, true); // [1,0,3,2]
    x += __int_as_float(y1);
    int y2 = __builtin_amdgcn_mov_dpp(__float_as_int(x), 0x4E, 0xF, 0xF, true); // [2,3,0,1]
    x += __int_as_float(y2);
    return x;
}

// In-loop register pin: redefines 4 float4s through an opaque asm each
// iteration. This makes the weights LOOP-CARRIED (phi cycle through the
// asm), so the RA cannot service them by re-loading from memory inside
// the loop (the R5-R9 failure: ~196KB/CU/step streamed from L1 = the
// constant ~2000 cyc/step across all five rounds). They must stay VGPRs.
#define PIN16(a, b, c, d)                                              \
    asm volatile("" : "+v"(a.x), "+v"(a.y), "+v"(a.z), "+v"(a.w),      \
                      "+v"(b.x), "+v"(b.y), "+v"(b.z), "+v"(b.w),      \
                      "+v"(c.x), "+v"(c.y), "+v"(c.z), "+v"(c.w),      \
                      "+v"(d.x), "+v"(d.y), "+v"(d.z), "+v"(d.w))

// Raw barrier: LDS-visibility sync WITHOUT the vmcnt(0) drain, so gate
// stores stay in flight across steps.
__device__ __forceinline__ void block_sync_lds() {
    asm volatile("s_waitcnt lgkmcnt(0)" ::: "memory");
    __builtin_amdgcn_s_barrier();
    __builtin_amdgcn_sched_barrier(0);
}

__device__ __forceinline__ float dot4(float4 w, float4 h, float s) {
    s = fmaf(w.x, h.x, s); s = fmaf(w.y, h.y, s);
    s = fmaf(w.z, h.z, s); s = fmaf(w.w, h.w, s);
    return s;
}

// Prologue: one block per (v,g); 128 threads = one output row each.
__global__ __launch_bounds__(128, 2)
void gv_prologue(const float* __restrict__ emb,
                 const float* __restrict__ Wf,
                 const float* __restrict__ Wc,
                 const float* __restrict__ Wo) {
    const int g = blockIdx.x % 3;
    const int v = blockIdx.x / 3;
    const int r = threadIdx.x;

    __shared__ __align__(16) float e_lds[EMBED];
    e_lds[r]       = emb[(size_t)v * EMBED + r];
    e_lds[r + 128] = emb[(size_t)v * EMBED + r + 128];
    __syncthreads();

    const float* Wg = (g == 0) ? Wf : (g == 1) ? Wo : Wc;
    const float4* wr = (const float4*)(Wg + (size_t)r * KX + HIDDEN);
    const float4* ev = (const float4*)e_lds;
    float a0 = 0.f, a1 = 0.f, a2 = 0.f, a3 = 0.f;
#pragma unroll
    for (int i = 0; i < EMBED / 4; ++i) {
        float4 w4 = wr[i];
        float4 e4 = ev[i];
        a0 += w4.x * e4.x;
        a1 += w4.y * e4.y;
        a2 += w4.z * e4.z;
        a3 += w4.w * e4.w;
    }
    Gv_buf[(size_t)v * 384 + g * 128 + r] = (a0 + a1) + (a2 + a3);
}

// Main recurrence: 256 blocks (1/CU) x 512 threads (8 waves, 2/SIMD).
// Thread = (r = tid>>2, q = tid&3): all 3 gates of row r, K-quarter q.
// 96 weight floats/thread in 24 NAMED float4s, pinned IN-LOOP.
// Budget audit: per-SIMD file = 512 regs; 2 waves/SIMD co-resident caps
// alloc at 256/wave; demand ~160 fits. waves_per_eu(1) relaxes the
// allocator's occupancy heuristic to that cap.
__global__ void __attribute__((amdgpu_flat_work_group_size(512, 512),
                               amdgpu_waves_per_eu(1)))
lstm_main(const int* __restrict__ tokens,
          const float* __restrict__ Wf,
          const float* __restrict__ Wc,
          const float* __restrict__ Wo,
          const float* __restrict__ clfW,
          const float* __restrict__ clfb,
          float* __restrict__ out) {
    const int b   = blockIdx.x;
    const int tid = threadIdx.x;        // 0..511
    const int q   = tid & 3;            // K-quarter / gate-lane
    const int r   = tid >> 2;           // 0..127 output row

    __shared__ __align__(16) float hbuf[2][4 * SEG];
    __shared__ int tok[SEQ];

    const float4* PF = (const float4*)(Wf + (size_t)r * KX + q * 32);
    const float4* PO = (const float4*)(Wo + (size_t)r * KX + q * 32);
    const float4* PC = (const float4*)(Wc + (size_t)r * KX + q * 32);
    float4 F0 = PF[0], F1 = PF[1], F2 = PF[2], F3 = PF[3];
    float4 F4 = PF[4], F5 = PF[5], F6 = PF[6], F7 = PF[7];
    float4 O0 = PO[0], O1 = PO[1], O2 = PO[2], O3 = PO[3];
    float4 O4 = PO[4], O5 = PO[5], O6 = PO[6], O7 = PO[7];
    float4 C0 = PC[0], C1 = PC[1], C2 = PC[2], C3 = PC[3];
    float4 C4 = PC[4], C5 = PC[5], C6 = PC[6], C7 = PC[7];

    tok[tid] = tokens[(size_t)b * SEQ + tid];        // 512 threads, 512 tokens
    if (tid < HIDDEN) hbuf[0][(tid >> 5) * SEG + (tid & 31)] = 0.f;
    float c = 0.f;                                   // replicated per quad lane
    __syncthreads();

    const size_t GATE0 = (size_t)BATCH * VOCAB;
    const size_t GSZ   = (size_t)SEQ * BATCH * HIDDEN;
    float* gout = out + GATE0 + (size_t)q * GSZ + (size_t)b * HIDDEN + r;

    for (int t = 0; t < SEQ; ++t) {
        // Re-pin all 96 weight components: forces VGPR residency this iter.
        PIN16(F0, F1, F2, F3); PIN16(F4, F5, F6, F7);
        PIN16(O0, O1, O2, O3); PIN16(O4, O5, O6, O7);
        PIN16(C0, C1, C2, C3); PIN16(C4, C5, C6, C7);

        const int p  = t & 1;
        const int tk = tok[t];
        const float gx = (q < 3) ? Gv_buf[tk * 384 + q * 128 + r] : 0.f;

        const float4* hv = (const float4*)&hbuf[p][q * SEG];
        float4 h0 = hv[0], h1 = hv[1], h2 = hv[2], h3 = hv[3];
        float4 h4 = hv[4], h5 = hv[5], h6 = hv[6], h7 = hv[7];

        float pf = 0.f, po = 0.f, pc = 0.f;
        pf = dot4(F0, h0, pf); pf = dot4(F1, h1, pf); pf = dot4(F2, h2, pf);
        pf = dot4(F3, h3, pf); pf = dot4(F4, h4, pf); pf = dot4(F5, h5, pf);
        pf = dot4(F6, h6, pf); pf = dot4(F7, h7, pf);
        po = dot4(O0, h0, po); po = dot4(O1, h1, po); po = dot4(O2, h2, po);
        po = dot4(O3, h3, po); po = dot4(O4, h4, po); po = dot4(O5, h5, po);
        po = dot4(O6, h6, po); po = dot4(O7, h7, po);
        pc = dot4(C0, h0, pc); pc = dot4(C1, h1, pc); pc = dot4(C2, h2, pc);
        pc = dot4(C3, h3, pc); pc = dot4(C4, h4, pc); pc = dot4(C5, h5, pc);
        pc = dot4(C6, h6, pc); pc = dot4(C7, h7, pc);

        pf += (q == 0) ? gx : 0.f;
        po += (q == 1) ? gx : 0.f;
        pc += (q == 2) ? gx : 0.f;

        const float pre_f = quad_sum(pf);
        const float pre_o = quad_sum(po);
        const float pre_c = quad_sum(pc);

        const float f  = fast_sigmoid(pre_f);
        const float o  = fast_sigmoid(pre_o);
        const float ct = fast_tanh(pre_c);
        c = fmaf(f, c - ct, ct);               // f*c + (1-f)*ct
        const float h = o * fast_tanh(c);

        if (q == 0) hbuf[1 - p][(r >> 5) * SEG + (r & 31)] = h;
        block_sync_lds();                      // lgkmcnt(0)+s_barrier, no vmcnt drain
        const float sval = (q == 0) ? f : (q == 1) ? o : ct;
        if (q < 3) gout[(size_t)t * (BATCH * HIDDEN)] = sval;
    }

    // Epilogue: logits[b][v] = h_T . clfW[v] + clfb[v]; h_T is in hbuf[0]
    if (tid < 4 * VOCAB) {
        const int v = tid >> 2;
        const float4* cw = (const float4*)(clfW + (size_t)v * HIDDEN + q * 32);
        const float4* hp = (const float4*)&hbuf[0][q * SEG];
        float a = 0.f;
#pragma unroll
        for (int i = 0; i < 8; ++i) a = dot4(cw[i], hp[i], a);
        a = quad_sum(a);
        if (q == 0) out[(size_t)b * VOCAB + v] = a + clfb[v];
    }
}

extern "C" void kernel_launch(void* const* d_in, const int* in_sizes, int n_in,
                              void* d_out, int out_size, void* d_ws, size_t ws_size,
                              hipStream_t stream) {
    const int*   tokens = (const int*)  d_in[0];
    const float* emb    = (const float*)d_in[1];
    const float* Wf     = (const float*)d_in[2];
    const float* Wc     = (const float*)d_in[3];
    const float* Wo     = (const float*)d_in[4];
    const float* clfW   = (const float*)d_in[5];
    const float* clfb   = (const float*)d_in[6];
    float*       out    = (float*)d_out;

    gv_prologue<<<3 * VOCAB, 128, 0, stream>>>(emb, Wf, Wc, Wo);
    lstm_main<<<BATCH, 512, 0, stream>>>(tokens, Wf, Wc, Wo, clfW, clfb, out);
}